// Round 10
// baseline (1072.576 us; speedup 1.0000x reference)
//
#include <hip/hip_runtime.h>

#define DEV __device__ __forceinline__
typedef unsigned int u32;
typedef unsigned long long u64;
typedef _Float16 f16;
typedef f16 h2 __attribute__((ext_vector_type(2)));
using pkv2 = decltype(__builtin_amdgcn_cvt_pkrtz(0.0f, 0.0f));

constexpr int nB = 8, nT = 128, nS = 512, nD = 128;
constexpr int NTH = 512;
constexpr int J   = 4;     // WGs per batch; each owns 128 encoder positions
constexpr int RS2 = 68;    // LDS row stride in u32 (64 + pad 4; 272B = 17x16B aligned)

// ws layout (u32 index) ----------------------------------------------------
constexpr int XW_W = 0;        // [b][t][256] f16x2: x@W cols (col pairs)
constexpr int HU_W = 262144;   // [b][s][64]  f16x2: HU rows (d pairs)
constexpr int WA_W = 524288;   // [col][64]   f16x2: Wa (row pairs)
constexpr int S1_W = 532480;   // u64 region: [b][j][parity][132]: 0..127=N,128=S

#if defined(__has_builtin)
#if __has_builtin(__builtin_amdgcn_fdot2)
#define HAS_FDOT2 1
#endif
#endif

DEV h2  u2h(u32 a) { return __builtin_bit_cast(h2, a); }
DEV u32 h2u(h2 a)  { return __builtin_bit_cast(u32, a); }
DEV u32 pkrtz(float a, float b) { return __builtin_bit_cast(u32, __builtin_amdgcn_cvt_pkrtz(a, b)); }

DEV float fdot2(u32 a, u32 b, float c) {
#ifdef HAS_FDOT2
    return __builtin_amdgcn_fdot2(__builtin_bit_cast(pkv2, a), __builtin_bit_cast(pkv2, b), c, false);
#else
    h2 A = u2h(a), B = u2h(b);
    return c + (float)A.x * (float)B.x + (float)A.y * (float)B.y;
#endif
}

// packed cubic tanh for score args (|x| <= ~0.3): tanh ~ x - x^3/3
DEV h2 tanh_pk(h2 x) {
    h2 x2 = x * x;
    h2 x3 = x * x2;
    h2 c3 = { (f16)0.33333333f, (f16)0.33333333f };
    return x - x3 * c3;
}
// fp32 Pade(7/6) tanh for gates
DEV float fast_tanh(float x) {
    x = fminf(4.0f, fmaxf(-4.0f, x));
    float x2 = x * x;
    float num = fmaf(fmaf(x2 + 378.0f, x2, 17325.0f), x2, 135135.0f);
    float den = fmaf(fmaf(fmaf(x2, 28.0f, 3150.0f), x2, 62370.0f), x2, 135135.0f);
    return x * num * __builtin_amdgcn_rcpf(den);
}
DEV float fast_sig(float x) { return fmaf(fast_tanh(0.5f * x), 0.5f, 0.5f); }

DEV u64  pk64(float v, unsigned t) { return ((u64)t << 32) | (u64)__float_as_uint(v); }
DEV void st64(u64* p, u64 v) { __hip_atomic_store(p, v, __ATOMIC_RELAXED, __HIP_MEMORY_SCOPE_AGENT); }
DEV u64  ld64(const u64* p)  { return __hip_atomic_load(p, __ATOMIC_RELAXED, __HIP_MEMORY_SCOPE_AGENT); }
DEV float poll64(const u64* p, unsigned want) {
    u64 q = ld64(p);
    while ((unsigned)(q >> 32) != want) { __builtin_amdgcn_s_sleep(1); q = ld64(p); }
    return __uint_as_float((unsigned)q);
}

// ---- pre-kernel: parallel startup GEMMs into ws (64 WGs) -----------------
__global__ __launch_bounds__(512, 1) void pre_kernel(
    const float* __restrict__ x,  const float* __restrict__ H,
    const float* __restrict__ Wa, const float* __restrict__ Ua,
    const float* __restrict__ Wi, const float* __restrict__ Wf,
    const float* __restrict__ Wc, const float* __restrict__ Wo,
    u32* __restrict__ ws)
{
    const int w = blockIdx.x, tid = threadIdx.x;
    if (w < 32) {
        const int b = w >> 2, tp = w & 3;
        const int g = tid >> 7, cc = tid & 127;
        const float* Wm = (g == 0) ? Wi : (g == 1) ? Wf : (g == 2) ? Wc : Wo;
        float wcol[128];
        #pragma unroll
        for (int r = 0; r < 128; ++r) wcol[r] = Wm[r * nD + cc];
        for (int ti = 0; ti < 32; ++ti) {
            int t = tp * 32 + ti;
            const float* xr = x + ((size_t)b * nT + t) * nD;
            float acc = 0.0f;
            #pragma unroll
            for (int r = 0; r < 128; ++r) acc = fmaf(xr[r], wcol[r], acc);
            float accn = __shfl_down(acc, 1);
            if (!(tid & 1))
                ws[XW_W + ((size_t)b * nT + t) * 256 + (tid >> 1)] = pkrtz(acc, accn);
        }
        if (w == 0) {
            int col = tid >> 2, q = tid & 3;
            #pragma unroll
            for (int k = 0; k < 16; ++k) {
                int rp = q * 16 + k;
                ws[WA_W + col * 64 + rp] =
                    pkrtz(Wa[(2 * rp) * nD + col], Wa[(2 * rp + 1) * nD + col]);
            }
        }
    } else {
        const int b = (w - 32) >> 2, sp4 = (w - 32) & 3;
        __shared__ float UaS[128 * 128];
        for (int k = tid; k < 16384; k += 512) UaS[k] = Ua[k];
        __syncthreads();
        const int lo = tid & 3, si = tid >> 2;
        const int s = sp4 * 128 + si;
        const float* hrow = H + ((size_t)b * nS + s) * nD;
        float acc[32];
        #pragma unroll
        for (int i = 0; i < 32; ++i) acc[i] = 0.0f;
        for (int r4 = 0; r4 < 32; ++r4) {
            float4 hv = ((const float4*)hrow)[r4];
            #pragma unroll
            for (int k = 0; k < 4; ++k) {
                float hr = (k == 0) ? hv.x : (k == 1) ? hv.y : (k == 2) ? hv.z : hv.w;
                const float4* ua = (const float4*)&UaS[(4 * r4 + k) * 128 + lo * 32];
                #pragma unroll
                for (int q = 0; q < 8; ++q) {
                    float4 u = ua[q];
                    acc[4*q+0] = fmaf(hr, u.x, acc[4*q+0]);
                    acc[4*q+1] = fmaf(hr, u.y, acc[4*q+1]);
                    acc[4*q+2] = fmaf(hr, u.z, acc[4*q+2]);
                    acc[4*q+3] = fmaf(hr, u.w, acc[4*q+3]);
                }
            }
        }
        u32* dst = ws + HU_W + ((size_t)b * nS + s) * 64 + lo * 16;
        #pragma unroll
        for (int k = 0; k < 16; ++k) dst[k] = pkrtz(acc[2 * k], acc[2 * k + 1]);
    }
}

// ---- main kernel: 32 WGs; WG (b,j) owns S-slice j; gates fully redundant -
__global__ __launch_bounds__(NTH, 1) void attn_lstm_kernel(
    const float* __restrict__ x,  const float* __restrict__ H,
    const float* __restrict__ init_states, const float* __restrict__ Wa,
    const float* __restrict__ Ua, const float* __restrict__ v,
    const float* __restrict__ Wi, const float* __restrict__ Ui,
    const float* __restrict__ Ci, const float* __restrict__ bi,
    const float* __restrict__ Wf, const float* __restrict__ Uf,
    const float* __restrict__ Cf, const float* __restrict__ bf,
    const float* __restrict__ Wc, const float* __restrict__ Uc,
    const float* __restrict__ Cc, const float* __restrict__ bc,
    const float* __restrict__ Wo, const float* __restrict__ Uo,
    const float* __restrict__ Co, const float* __restrict__ bo,
    float* __restrict__ out, u32* __restrict__ ws)
{
    const int tid = threadIdx.x;
    const int b = blockIdx.x & 7, j = blockIdx.x >> 3;

    u64* S1 = (u64*)(ws + S1_W);

    __shared__ __align__(16) u32 Hl[128 * RS2];    // H^T f16 slice (34.8 KB)
    __shared__ __align__(16) u32 HUl[128 * RS2];   // HU f16 slice  (34.8 KB)
    __shared__ __align__(16) u32 h_l[64], q_l[64], ctx_l[64], e_l[64], v_w[64];
    __shared__ __align__(16) float sc_l[128], pNx[512], pN2[384], pre_l[512];
    __shared__ float mS2[4];

    // roles
    const int g = tid >> 7, cc = tid & 127;   // gate col = tid
    const int qc = tid >> 2, qr = tid & 3;    // q phase
    const int hi = tid >> 2, lo = tid & 3;    // score phase: local pos, d-quarter
    const int d2 = tid & 127, q4 = tid >> 7;  // ctx-partial phase
    const int wv = tid >> 6, ln = tid & 63;   // wave id, lane

    const float* Ug = (g == 0) ? Ui : (g == 1) ? Uf : (g == 2) ? Uc : Uo;
    const float* Cg = (g == 0) ? Ci : (g == 1) ? Cf : (g == 2) ? Cc : Co;
    const float* Bg = (g == 0) ? bi : (g == 1) ? bf : (g == 2) ? bc : bo;

    // ---- startup: H^T f16 slice into Hl (thread: pos-pair pp, d-group dq)
    {
        const int pp = tid >> 3, dq = tid & 7;
        const float* r0 = H + ((size_t)b * nS + (size_t)128 * j + 2 * pp) * nD + dq * 16;
        const float* r1 = r0 + nD;
        #pragma unroll
        for (int k = 0; k < 4; ++k) {
            float4 a = ((const float4*)r0)[k];
            float4 c = ((const float4*)r1)[k];
            int d0 = dq * 16 + 4 * k;
            Hl[(d0 + 0) * RS2 + pp] = pkrtz(a.x, c.x);
            Hl[(d0 + 1) * RS2 + pp] = pkrtz(a.y, c.y);
            Hl[(d0 + 2) * RS2 + pp] = pkrtz(a.z, c.z);
            Hl[(d0 + 3) * RS2 + pp] = pkrtz(a.w, c.w);
        }
    }
    // ---- startup: HU f16 slice into HUl[pos*RS2 + dpair]
    {
        const int s = tid >> 2, wq = (tid & 3) * 16;
        const u32* src = ws + HU_W + ((size_t)b * nS + (size_t)128 * j + s) * 64 + wq;
        #pragma unroll
        for (int q = 0; q < 4; ++q)
            *(uint4*)&HUl[s * RS2 + wq + 4 * q] = ((const uint4*)src)[q];
    }
    if (tid < 64) v_w[tid] = pkrtz(v[2 * tid], v[2 * tid + 1]);

    // ---- resident registers: Wa quarter + full U/C columns
    u32 wa_r[16];
    {
        const uint4* wp = (const uint4*)(ws + WA_W + qc * 64 + qr * 16);
        #pragma unroll
        for (int q = 0; q < 4; ++q) {
            uint4 t4 = wp[q];
            wa_r[4*q+0] = t4.x; wa_r[4*q+1] = t4.y; wa_r[4*q+2] = t4.z; wa_r[4*q+3] = t4.w;
        }
    }
    u32 Ur[64], Cr[64];
    #pragma unroll
    for (int rp = 0; rp < 64; ++rp) {
        Ur[rp] = pkrtz(Ug[(2*rp) * nD + cc], Ug[(2*rp+1) * nD + cc]);
        Cr[rp] = pkrtz(Cg[(2*rp) * nD + cc], Cg[(2*rp+1) * nD + cc]);
    }
    const float bval = Bg[cc];

    float c_reg = 0.0f;
    if (tid < 128) c_reg = init_states[nB * nD + b * nD + tid];
    if (tid < 128 && !(tid & 1))
        h_l[tid >> 1] = pkrtz(init_states[b * nD + tid], init_states[b * nD + tid + 1]);
    __syncthreads();

    for (int t = 0; t < nT; ++t) {
        const unsigned tg = (unsigned)(t + 1);
        const int par = t & 1;
        u64* myN = S1 + (size_t)(((b * J + j) * 2) + par) * 132;

        // prefetch XW word (consumed after B7)
        u32 xww = ws[XW_W + ((size_t)b * nT + t) * 256 + (tid >> 1)];

        // ---- A: ud = U[:,col]·h (full); qa = Wa-quarter·h
        float ud = 0.0f, qa = 0.0f;
        #pragma unroll
        for (int ch = 0; ch < 16; ++ch) {
            uint4 hw = ((const uint4*)h_l)[ch];
            ud = fdot2(Ur[4*ch+0], hw.x, ud);
            ud = fdot2(Ur[4*ch+1], hw.y, ud);
            ud = fdot2(Ur[4*ch+2], hw.z, ud);
            ud = fdot2(Ur[4*ch+3], hw.w, ud);
        }
        #pragma unroll
        for (int q = 0; q < 4; ++q) {
            uint4 hw = ((const uint4*)h_l)[qr * 4 + q];
            qa = fdot2(wa_r[4*q+0], hw.x, qa);
            qa = fdot2(wa_r[4*q+1], hw.y, qa);
            qa = fdot2(wa_r[4*q+2], hw.z, qa);
            qa = fdot2(wa_r[4*q+3], hw.w, qa);
        }
        qa += __shfl_xor(qa, 1);
        qa += __shfl_xor(qa, 2);
        if (qr == 0 && !(qc & 1)) {
            float qn = __shfl_down(qa, 4);
            q_l[qc >> 1] = pkrtz(qa, qn);
        }
        __syncthreads();   // B1

        // ---- score: pos hi, d-quarter lo (HU from LDS)
        float sa = 0.0f;
        {
            const u32* hup = &HUl[hi * RS2 + lo * 16];
            #pragma unroll
            for (int q = 0; q < 4; ++q) {
                uint4 hu = ((const uint4*)hup)[q];
                uint4 qv = ((const uint4*)q_l)[lo * 4 + q];
                uint4 vv = ((const uint4*)v_w)[lo * 4 + q];
                h2 x0 = u2h(hu.x) + u2h(qv.x);
                h2 x1 = u2h(hu.y) + u2h(qv.y);
                h2 x2 = u2h(hu.z) + u2h(qv.z);
                h2 x3 = u2h(hu.w) + u2h(qv.w);
                sa = fdot2(vv.x, h2u(tanh_pk(x0)), sa);
                sa = fdot2(vv.y, h2u(tanh_pk(x1)), sa);
                sa = fdot2(vv.z, h2u(tanh_pk(x2)), sa);
                sa = fdot2(vv.w, h2u(tanh_pk(x3)), sa);
            }
            sa += __shfl_xor(sa, 1);
            sa += __shfl_xor(sa, 2);
            if (lo == 0) sc_l[hi] = sa;
        }
        __syncthreads();   // B2

        // ---- softmax over 128 local scores (per-wave redundant, no-max)
        float se;
        {
            float2 sp = ((const float2*)sc_l)[ln];
            float e0 = __expf(sp.x), e1 = __expf(sp.y);
            se = e0 + e1;
            #pragma unroll
            for (int o = 1; o < 64; o <<= 1) se += __shfl_xor(se, o);
            e_l[ln] = pkrtz(e0, e1);
        }
        __syncthreads();   // B3

        // ---- ctx partial: thread (d2, q4) over 16 s-pairs
        {
            float na = 0.0f;
            const u32* hp = &Hl[d2 * RS2 + q4 * 16];
            const u32* ep = &e_l[q4 * 16];
            #pragma unroll
            for (int k = 0; k < 4; ++k) {
                uint4 hh = ((const uint4*)hp)[k];
                uint4 ee = ((const uint4*)ep)[k];
                na = fdot2(hh.x, ee.x, na);
                na = fdot2(hh.y, ee.y, na);
                na = fdot2(hh.z, ee.z, na);
                na = fdot2(hh.w, ee.w, na);
            }
            pNx[q4 * 128 + d2] = na;
        }
        __syncthreads();   // B4

        // ---- exchange: wave 0 publishes; waves 1-3 poll one partner each
        if (wv == 0) {
            float2 a0 = ((const float2*)pNx)[ln];
            float2 a1 = ((const float2*)pNx)[64 + ln];
            float2 a2 = ((const float2*)pNx)[128 + ln];
            float2 a3 = ((const float2*)pNx)[192 + ln];
            float n0 = a0.x + a1.x + a2.x + a3.x;
            float n1 = a0.y + a1.y + a2.y + a3.y;
            st64(myN + 2 * ln,     pk64(n0, tg));
            st64(myN + 2 * ln + 1, pk64(n1, tg));
            if (ln == 0) st64(myN + 128, pk64(se, tg));
        } else if (wv < 4) {
            int pi = wv - 1, jj = pi + (pi >= j);
            const u64* P = S1 + (size_t)(((b * J + jj) * 2) + par) * 132;
            pN2[pi * 128 + 2 * ln]     = poll64(P + 2 * ln, tg);
            pN2[pi * 128 + 2 * ln + 1] = poll64(P + 2 * ln + 1, tg);
            if (ln == 0) mS2[pi] = poll64(P + 128, tg);
        }
        __syncthreads();   // B5

        // ---- ctx combine (canonical order -> bitwise-identical across WGs)
        if (tid < 128) {
            float Nown = pNx[tid] + pNx[128 + tid] + pNx[256 + tid] + pNx[384 + tid];
            float nsum = 0.0f, ssum = 0.0f;
            #pragma unroll
            for (int jj = 0; jj < 4; ++jj) {
                int sl = jj - (jj > j);
                float nv = (jj == j) ? Nown : pN2[sl * 128 + tid];
                float sv = (jj == j) ? se   : mS2[sl];
                nsum += nv; ssum += sv;
            }
            float ctxv = nsum * __builtin_amdgcn_rcpf(ssum);
            float cn = __shfl_down(ctxv, 1);
            if (!(tid & 1)) ctx_l[tid >> 1] = pkrtz(ctxv, cn);
        }
        __syncthreads();   // B6

        // ---- cd = C[:,col]·ctx ; gate pre-activation
        {
            float cd = 0.0f;
            #pragma unroll
            for (int ch = 0; ch < 16; ++ch) {
                uint4 cw = ((const uint4*)ctx_l)[ch];
                cd = fdot2(Cr[4*ch+0], cw.x, cd);
                cd = fdot2(Cr[4*ch+1], cw.y, cd);
                cd = fdot2(Cr[4*ch+2], cw.z, cd);
                cd = fdot2(Cr[4*ch+3], cw.w, cd);
            }
            h2 xwp = u2h(xww);
            float xwv = (tid & 1) ? (float)xwp.y : (float)xwp.x;
            pre_l[tid] = ud + cd + xwv + bval;
        }
        __syncthreads();   // B7

        // ---- LSTM update (redundant in every WG); only j==0 stores out
        if (tid < 128) {
            float ig = fast_sig(pre_l[tid]);
            float fg = fast_sig(pre_l[128 + tid]);
            float gg = fast_tanh(pre_l[256 + tid]);
            float og = fast_sig(pre_l[384 + tid]);
            c_reg = fmaf(fg, c_reg, ig * gg);
            float hn = og * fast_tanh(c_reg);
            if (j == 0) out[((size_t)b * nT + t) * nD + tid] = hn;
            float hnn = __shfl_down(hn, 1);
            if (!(tid & 1)) h_l[tid >> 1] = pkrtz(hn, hnn);
        }
        __syncthreads();   // B8
    }
}

extern "C" void kernel_launch(void* const* d_in, const int* in_sizes, int n_in,
                              void* d_out, int out_size, void* d_ws, size_t ws_size,
                              hipStream_t stream) {
    const float* x  = (const float*)d_in[0];
    const float* H  = (const float*)d_in[1];
    const float* is = (const float*)d_in[2];
    const float* Wa = (const float*)d_in[3];
    const float* Ua = (const float*)d_in[4];
    const float* v  = (const float*)d_in[5];
    const float* Wi = (const float*)d_in[6];
    const float* Ui = (const float*)d_in[7];
    const float* Ci = (const float*)d_in[8];
    const float* bi = (const float*)d_in[9];
    const float* Wf = (const float*)d_in[10];
    const float* Uf = (const float*)d_in[11];
    const float* Cf = (const float*)d_in[12];
    const float* bf = (const float*)d_in[13];
    const float* Wc = (const float*)d_in[14];
    const float* Uc = (const float*)d_in[15];
    const float* Cc = (const float*)d_in[16];
    const float* bc = (const float*)d_in[17];
    const float* Wo = (const float*)d_in[18];
    const float* Uo = (const float*)d_in[19];
    const float* Co = (const float*)d_in[20];
    const float* bo = (const float*)d_in[21];
    float* out = (float*)d_out;
    u32*   ws  = (u32*)d_ws;

    hipLaunchKernelGGL(pre_kernel, dim3(64), dim3(512), 0, stream,
                       x, H, Wa, Ua, Wi, Wf, Wc, Wo, ws);
    hipLaunchKernelGGL(attn_lstm_kernel, dim3(nB * J), dim3(NTH), 0, stream,
                       x, H, is, Wa, Ua, v,
                       Wi, Ui, Ci, bi, Wf, Uf, Cf, bf,
                       Wc, Uc, Cc, bc, Wo, Uo, Co, bo,
                       out, ws);
}